// Round 3
// baseline (330.825 us; speedup 1.0000x reference)
//
#include <hip/hip_runtime.h>

// ---------------------------------------------------------------------------
// SpatialTransformer attention, dtype-robust (fp32 vs bf16 storage detect).
// Round 6 (3rd submit; rounds 1-2 died on infra: GPUAcquisitionTimeout, then
// container-failed-twice — no on-device signal either time).  QKV + QK^T on
// a 256x256 8-phase pipelined core (T2 LDS XOR-swizzle + T3/T4 counted-vmcnt
// phases + T5 setprio, per the verified gemm_256sq_8phase template).
// Schedule ledger: stage stream per K-tile = [B0,B1,A0,A1], issue depth 6
// phases, one vmcnt(4) per K-tile (vmcnt(0) only at tiles NT-2, NT-1).
// PV and OUT keep the round-5 128x128 core (256-tile grids there would be
// 128 blocks = half the CUs idle).
// ---------------------------------------------------------------------------

typedef __attribute__((ext_vector_type(8))) short short8;
typedef __attribute__((ext_vector_type(8))) unsigned short ushort8;
typedef __attribute__((ext_vector_type(4))) unsigned short ushort4v;
typedef __attribute__((ext_vector_type(4))) float f32x4;

__device__ __forceinline__ float b2f(unsigned short u) {
  union { unsigned int i; float f; } x;
  x.i = ((unsigned int)u) << 16;
  return x.f;
}
__device__ __forceinline__ unsigned short f2b(float f) {
  union { float f; unsigned int i; } x;
  x.f = f;
  unsigned int i = x.i;
  i += 0x7fffu + ((i >> 16) & 1u);  // RNE
  return (unsigned short)(i >> 16);
}

__device__ __forceinline__ void async_copy16(const void* g, void* l) {
  __builtin_amdgcn_global_load_lds(
      (const __attribute__((address_space(1))) unsigned int*)g,
      (__attribute__((address_space(3))) unsigned int*)l, 16, 0, 0);
}

// --- storage-format detector: fp32 storage => even ushorts are mantissa bits
__global__ void detect_fmt(const unsigned short* __restrict__ x, int* flag) {
  __shared__ int cnt;
  if (threadIdx.x == 0) cnt = 0;
  __syncthreads();
  int c = 0;
  for (int i = threadIdx.x * 2; i < 8192; i += 512) {
    unsigned e = (x[i] >> 7) & 0xFF;
    if (e >= 0x90) ++c;
  }
  atomicAdd(&cnt, c);
  __syncthreads();
  if (threadIdx.x == 0) *flag = (cnt > 64) ? 1 : 0;
}

// --- one fused conversion of all 10 inputs into a contiguous bf16 concat
struct CvtArgs { const void* src[10]; };

__global__ __launch_bounds__(256) void convert_all(
    CvtArgs a, unsigned short* __restrict__ dst, const int* __restrict__ flag) {
  const bool f32 = (*flag != 0);
  const long nchunk = 2621952;  // 20975616 / 8
  for (long c = blockIdx.x * 256L + threadIdx.x; c < nchunk;
       c += 1024L * 256) {
    const long flat = c * 8;
    int t; long off;
    if      (flat < 8388608)  { t = 0; off = 0; }
    else if (flat < 16777216) { t = 1; off = 8388608; }
    else if (flat < 17825792) { t = 2; off = 16777216; }
    else if (flat < 17826816) { t = 3; off = 17825792; }
    else if (flat < 18875392) { t = 4; off = 17826816; }
    else if (flat < 18876416) { t = 5; off = 18875392; }
    else if (flat < 19924992) { t = 6; off = 18876416; }
    else if (flat < 19926016) { t = 7; off = 19924992; }
    else if (flat < 20974592) { t = 8; off = 19926016; }
    else                      { t = 9; off = 20974592; }
    const long li = flat - off;
    if (f32) {
      const float* s = (const float*)a.src[t] + li;
      const f32x4 lo = *(const f32x4*)s;
      const f32x4 hi = *(const f32x4*)(s + 4);
      ushort8 o;
      o[0] = f2b(lo[0]); o[1] = f2b(lo[1]); o[2] = f2b(lo[2]); o[3] = f2b(lo[3]);
      o[4] = f2b(hi[0]); o[5] = f2b(hi[1]); o[6] = f2b(hi[2]); o[7] = f2b(hi[3]);
      *(ushort8*)(dst + flat) = o;
    } else {
      *(ushort8*)(dst + flat) =
          *(const ushort8*)((const unsigned short*)a.src[t] + li);
    }
  }
}

#define MODE_BIAS 0  // bf16 out = acc + bias[n]  (vt: transposed V^T store)
#define MODE_RES  2  // bf16 out = acc + res[m,n]
#define MODE_SB   3  // bf16 out = acc * scale
#define MODE_OUT  4  // format-aware out = acc + bias[n]  (fp32 or bf16 store)

// XCD-band swizzle: round-robin XCD = linear%8 (assumed); blocks sharing a
// logical `by` (same A row-tile) land on one XCD, bx sweeping 0..gx.
// Requires gy % 8 == 0 and (gx*gy) % 8 == 0 (true for all our grids).
__device__ __forceinline__ void xcd_swizzle(int gx, int gy, int& bx, int& by) {
  const int L = blockIdx.y * gx + blockIdx.x;
  const int r = L & 7, m = L >> 3;
  bx = m % gx;
  by = r * (gy >> 3) + m / gx;
}

// ===========================================================================
// OLD 128x128 core (round-5, verified) — kept for PV (MODE_RES) and OUT.
// ===========================================================================
template <int MODE, int KU>
__device__ __forceinline__ void gemm_core(
    const unsigned short* __restrict__ A, const unsigned short* __restrict__ B,
    void* __restrict__ C, const unsigned short* __restrict__ bias,
    const unsigned short* __restrict__ Res, const int* __restrict__ flg,
    int N, int K, float scale, int bx, int by, int vt) {
  __shared__ __align__(16) unsigned short As[KU * 128 * 32];
  __shared__ __align__(16) unsigned short Bs[KU * 128 * 32];
  const int tid = threadIdx.x;
  const int wave = tid >> 6, lane = tid & 63;
  const int wm = wave >> 1, wn = wave & 1;
  const int quad = lane >> 4, lrow = lane & 15;

  const long arow0 = (long)by * 128 + (tid >> 2);
  const long brow0 = (long)bx * 128 + (tid >> 2);
  const int cstg = (tid & 3) * 8;
  const unsigned short* ag0 = A + arow0 * K + cstg;
  const unsigned short* ag1 = ag0 + 64L * K;
  const unsigned short* bg0 = B + brow0 * K + cstg;
  const unsigned short* bg1 = bg0 + 64L * K;
  char* lA0 = (char*)As + tid * 16;
  char* lA1 = (char*)As + (256 + tid) * 16;
  char* lB0 = (char*)Bs + tid * 16;
  char* lB1 = (char*)Bs + (256 + tid) * 16;

  f32x4 acc[4][4];
#pragma unroll
  for (int i = 0; i < 4; ++i)
#pragma unroll
    for (int j = 0; j < 4; ++j) acc[i][j] = (f32x4){0.f, 0.f, 0.f, 0.f};

  for (int kt = 0; kt < K; kt += 32 * KU) {
#pragma unroll
    for (int u = 0; u < KU; ++u) {
      async_copy16(ag0 + kt + u * 32, lA0 + u * 8192);
      async_copy16(ag1 + kt + u * 32, lA1 + u * 8192);
      async_copy16(bg0 + kt + u * 32, lB0 + u * 8192);
      async_copy16(bg1 + kt + u * 32, lB1 + u * 8192);
    }
    __syncthreads();
#pragma unroll
    for (int u = 0; u < KU; ++u) {
      const unsigned short* Au = As + u * 4096;
      const unsigned short* Bu = Bs + u * 4096;
      short8 af[4], bfr[4];
#pragma unroll
      for (int i = 0; i < 4; ++i)
        af[i] = *(const short8*)(Au + (wm * 64 + i * 16 + lrow) * 32 + quad * 8);
#pragma unroll
      for (int j = 0; j < 4; ++j)
        bfr[j] =
            *(const short8*)(Bu + (wn * 64 + j * 16 + lrow) * 32 + quad * 8);
#pragma unroll
      for (int i = 0; i < 4; ++i)
#pragma unroll
        for (int j = 0; j < 4; ++j)
          acc[i][j] = __builtin_amdgcn_mfma_f32_16x16x32_bf16(
              af[i], bfr[j], acc[i][j], 0, 0, 0);
    }
    __syncthreads();
  }

  const bool f32out = (MODE == MODE_OUT) ? (*flg != 0) : false;
  // C/D layout: col=lane&15, row=(lane>>4)*4+reg (m89-verified)
#pragma unroll
  for (int i = 0; i < 4; ++i) {
    const long row = (long)by * 128 + wm * 64 + i * 16 + quad * 4;
#pragma unroll
    for (int j = 0; j < 4; ++j) {
      const long col = (long)bx * 128 + wn * 64 + j * 16 + lrow;
      if (MODE == MODE_BIAS && vt) {
        const float bb = b2f(bias[col]);
        ushort4v pk;
#pragma unroll
        for (int r = 0; r < 4; ++r) pk[r] = f2b(acc[i][j][r] + bb);
        const long b = row >> 11, kvr = row & 2047;
        *(ushort4v*)((unsigned short*)C + b * 2097152 + col * 2048 + kvr) = pk;
        continue;
      }
#pragma unroll
      for (int r = 0; r < 4; ++r) {
        const float v = acc[i][j][r];
        const long idx = (row + r) * N + col;
        if (MODE == MODE_BIAS) {
          ((unsigned short*)C)[idx] = f2b(v + b2f(bias[col]));
        } else if (MODE == MODE_SB) {
          ((unsigned short*)C)[idx] = f2b(v * scale);
        } else if (MODE == MODE_RES) {
          ((unsigned short*)C)[idx] = f2b(v + b2f(Res[idx]));
        } else {  // MODE_OUT
          const float o = v + b2f(bias[col]);
          if (f32out) ((float*)C)[idx] = o;
          else        ((unsigned short*)C)[idx] = f2b(o);
        }
      }
    }
  }
}

template <int MODE, int KU>
__global__ __launch_bounds__(256, 2) void gemm_nt(
    const unsigned short* __restrict__ A, const unsigned short* __restrict__ B,
    void* __restrict__ C, const unsigned short* __restrict__ bias,
    const unsigned short* __restrict__ Res, const int* __restrict__ flg,
    int N, int K, float scale, long sA, long sB, long sC, long sR) {
  const int bz = blockIdx.z;
  int bx, by;
  xcd_swizzle(gridDim.x, gridDim.y, bx, by);
  const unsigned short* Rb = (MODE == MODE_RES) ? Res + bz * sR : nullptr;
  void* Cb = (MODE == MODE_OUT) ? (void*)((char*)C)
                                : (void*)((unsigned short*)C + bz * sC);
  gemm_core<MODE, KU>(A + bz * sA, B + bz * sB, Cb, bias, Rb, flg, N, K, scale,
                      bx, by, 0);
}

// ===========================================================================
// NEW 256x256 8-phase core (T2+T3+T4+T5), 512 threads = 8 waves (2M x 4N),
// BK=64, LDS 128 KiB double-buffered, per-wave output 128x64.
//
// LDS layout (bytes): A buf p at p*32768, B buf p at 65536 + p*32768.
// Tile = 256 rows x 64 cols bf16, row stride 128 B; swizzle: the 16B chunk
// at (row, ch) is stored at chunk position ch ^ (row&7)  (involution).
// global_load_lds dest stays LINEAR; the swizzle is applied by permuting
// the per-thread GLOBAL source chunk (rule #21) and on every ds_read_b128.
//
// Stage stream per K-tile T: [B0,B1,A0,A1] (= stream idx 4T..4T+3), one
// half-tile (2 loads/thread) per phase, issue depth D = 6 phases:
//   ph0 -> A0(t+1), ph1 -> A1(t+1), ph2 -> B0(t+2), ph3 -> B1(t+2)
// One vmcnt(4) per K-tile at ph3 (2 halves = 4 loads stay in flight);
// vmcnt(0) only at t = NT-2, NT-1.  Overwrite safety: B halves' last
// ds_read completes (lgkmcnt(0), register-landed) before phase 1's closing
// barrier; stageB(t+2) issues at phase >= 2.  A stages target the opposite
// buffer ((t+1)&1 != t&1).
// ===========================================================================
template <int MODE>
__device__ __forceinline__ void gemm256_core(
    const unsigned short* __restrict__ A, const unsigned short* __restrict__ B,
    void* __restrict__ C, const unsigned short* __restrict__ bias,
    const unsigned short* __restrict__ Res, const int* __restrict__ flg,
    int N, int K, float scale, int bx, int by, int vt) {
  __shared__ __align__(16) unsigned short lds[65536];  // 128 KiB
  const int tid = threadIdx.x;
  const int wave = tid >> 6, lane = tid & 63;
  const int wm = wave >> 2, wn = wave & 3;        // 2 x 4 wave grid
  const int quad = lane >> 4, lrow = lane & 15;
  const int NT = K >> 6;                           // K-tiles of 64

  // --- staging map: thread tid covers linear LDS bytes tid*16 (+8192 for
  // issue 1) of the target half; logical source chunk is pre-swizzled.
  const int srow = tid >> 3;                       // 0..63 (issue0 row)
  const int sch = (tid & 7) ^ (srow & 7);          // swizzled source chunk
  const unsigned short* gA = A + (long)(by * 256 + srow) * K + sch * 8;
  const unsigned short* gB = B + (long)(bx * 256 + srow) * K + sch * 8;
  char* const ldst = (char*)lds + tid * 16;

  auto stageA = [&](int ts, int h) {
    const unsigned short* g = gA + (long)h * 128 * K + ts * 64;
    char* l = ldst + (ts & 1) * 32768 + h * 16384;
    async_copy16(g, l);
    async_copy16(g + (long)64 * K, l + 8192);
  };
  auto stageB = [&](int ts, int h) {
    const unsigned short* g = gB + (long)h * 128 * K + ts * 64;
    char* l = ldst + 65536 + (ts & 1) * 32768 + h * 16384;
    async_copy16(g, l);
    async_copy16(g + (long)64 * K, l + 8192);
  };

  // fragment-read swizzled chunk offsets (elements); row&7 == lrow&7
  const int chk0 = ((quad) ^ (lrow & 7)) << 3;       // k-slice 0
  const int chk1 = ((4 + quad) ^ (lrow & 7)) << 3;   // k-slice 1

  f32x4 acc[8][4];
#pragma unroll
  for (int i = 0; i < 8; ++i)
#pragma unroll
    for (int j = 0; j < 4; ++j) acc[i][j] = (f32x4){0.f, 0.f, 0.f, 0.f};

  // --- prologue: stream halves 0..5 (tile0 complete + tile1 B halves)
  stageB(0, 0); stageB(0, 1); stageA(0, 0); stageA(0, 1);
  stageB(1, 0); stageB(1, 1);
  asm volatile("s_waitcnt vmcnt(4)" ::: "memory");  // tile0's 8 loads done
  __builtin_amdgcn_s_barrier();

  for (int t = 0; t < NT; ++t) {
    const unsigned short* Au = lds + (t & 1) * 16384 + (wm * 128 + lrow) * 64;
    const unsigned short* Bu =
        lds + 32768 + (t & 1) * 16384 + (wn * 64 + lrow) * 64;
    short8 a[4][2], blo[2][2], bhi[2][2];

    // ---- phase 0: quadrant (m-lo, n-lo); 12 ds_reads; stage A0(t+1)
#pragma unroll
    for (int i = 0; i < 4; ++i) {
      a[i][0] = *(const short8*)(Au + i * 1024 + chk0);
      a[i][1] = *(const short8*)(Au + i * 1024 + chk1);
    }
#pragma unroll
    for (int j = 0; j < 2; ++j) {
      blo[j][0] = *(const short8*)(Bu + j * 1024 + chk0);
      blo[j][1] = *(const short8*)(Bu + j * 1024 + chk1);
    }
    if (t + 1 < NT) stageA(t + 1, 0);
    __builtin_amdgcn_s_barrier();
    asm volatile("s_waitcnt lgkmcnt(0)" ::: "memory");
    __builtin_amdgcn_sched_barrier(0);
    __builtin_amdgcn_s_setprio(1);
#pragma unroll
    for (int i = 0; i < 4; ++i)
#pragma unroll
      for (int j = 0; j < 2; ++j) {
        acc[i][j] = __builtin_amdgcn_mfma_f32_16x16x32_bf16(
            a[i][0], blo[j][0], acc[i][j], 0, 0, 0);
        acc[i][j] = __builtin_amdgcn_mfma_f32_16x16x32_bf16(
            a[i][1], blo[j][1], acc[i][j], 0, 0, 0);
      }
    __builtin_amdgcn_s_setprio(0);
    __builtin_amdgcn_s_barrier();

    // ---- phase 1: (m-lo, n-hi); 4 ds_reads; stage A1(t+1)
#pragma unroll
    for (int j = 0; j < 2; ++j) {
      bhi[j][0] = *(const short8*)(Bu + (j + 2) * 1024 + chk0);
      bhi[j][1] = *(const short8*)(Bu + (j + 2) * 1024 + chk1);
    }
    if (t + 1 < NT) stageA(t + 1, 1);
    __builtin_amdgcn_s_barrier();
    asm volatile("s_waitcnt lgkmcnt(0)" ::: "memory");
    __builtin_amdgcn_sched_barrier(0);
    __builtin_amdgcn_s_setprio(1);
#pragma unroll
    for (int i = 0; i < 4; ++i)
#pragma unroll
      for (int j = 0; j < 2; ++j) {
        acc[i][j + 2] = __builtin_amdgcn_mfma_f32_16x16x32_bf16(
            a[i][0], bhi[j][0], acc[i][j + 2], 0, 0, 0);
        acc[i][j + 2] = __builtin_amdgcn_mfma_f32_16x16x32_bf16(
            a[i][1], bhi[j][1], acc[i][j + 2], 0, 0, 0);
      }
    __builtin_amdgcn_s_setprio(0);
    __builtin_amdgcn_s_barrier();

    // ---- phase 2: (m-hi, n-hi); 8 ds_reads (A frags 4-7); stage B0(t+2)
#pragma unroll
    for (int i = 0; i < 4; ++i) {
      a[i][0] = *(const short8*)(Au + (i + 4) * 1024 + chk0);
      a[i][1] = *(const short8*)(Au + (i + 4) * 1024 + chk1);
    }
    if (t + 2 < NT) stageB(t + 2, 0);
    __builtin_amdgcn_s_barrier();
    asm volatile("s_waitcnt lgkmcnt(0)" ::: "memory");
    __builtin_amdgcn_sched_barrier(0);
    __builtin_amdgcn_s_setprio(1);
#pragma unroll
    for (int i = 0; i < 4; ++i)
#pragma unroll
      for (int j = 0; j < 2; ++j) {
        acc[i + 4][j + 2] = __builtin_amdgcn_mfma_f32_16x16x32_bf16(
            a[i][0], bhi[j][0], acc[i + 4][j + 2], 0, 0, 0);
        acc[i + 4][j + 2] = __builtin_amdgcn_mfma_f32_16x16x32_bf16(
            a[i][1], bhi[j][1], acc[i + 4][j + 2], 0, 0, 0);
      }
    __builtin_amdgcn_s_setprio(0);
    __builtin_amdgcn_s_barrier();

    // ---- phase 3: (m-hi, n-lo); 0 ds_reads; stage B1(t+2); K-tile vmcnt
    if (t + 2 < NT) stageB(t + 2, 1);
    __builtin_amdgcn_s_barrier();
    __builtin_amdgcn_s_setprio(1);
#pragma unroll
    for (int i = 0; i < 4; ++i)
#pragma unroll
      for (int j = 0; j < 2; ++j) {
        acc[i + 4][j] = __builtin_amdgcn_mfma_f32_16x16x32_bf16(
            a[i][0], blo[j][0], acc[i + 4][j], 0, 0, 0);
        acc[i + 4][j] = __builtin_amdgcn_mfma_f32_16x16x32_bf16(
            a[i][1], blo[j][1], acc[i + 4][j], 0, 0, 0);
      }
    __builtin_amdgcn_s_setprio(0);
    if (t + 2 < NT) {
      asm volatile("s_waitcnt vmcnt(4)" ::: "memory");
    } else {
      asm volatile("s_waitcnt vmcnt(0)" ::: "memory");
    }
    __builtin_amdgcn_s_barrier();
  }

  // --- epilogue: C/D layout col=lane&15, row=(lane>>4)*4+reg (m89-verified)
  const bool f32out = (MODE == MODE_OUT) ? (*flg != 0) : false;
  float bb[4];
  if (MODE == MODE_BIAS || MODE == MODE_OUT) {
#pragma unroll
    for (int j = 0; j < 4; ++j)
      bb[j] = b2f(bias[(long)bx * 256 + wn * 64 + j * 16 + lrow]);
  }
#pragma unroll
  for (int i = 0; i < 8; ++i) {
    const long row = (long)by * 256 + wm * 128 + i * 16 + quad * 4;
#pragma unroll
    for (int j = 0; j < 4; ++j) {
      const long col = (long)bx * 256 + wn * 64 + j * 16 + lrow;
      if (MODE == MODE_BIAS && vt) {
        // V^T store: Vt[b][col][kv], 4 consecutive rows -> one 8B store
        ushort4v pk;
#pragma unroll
        for (int r = 0; r < 4; ++r) pk[r] = f2b(acc[i][j][r] + bb[j]);
        const long b = row >> 11, kvr = row & 2047;
        *(ushort4v*)((unsigned short*)C + b * 2097152 + col * 2048 + kvr) = pk;
        continue;
      }
#pragma unroll
      for (int r = 0; r < 4; ++r) {
        const float v = acc[i][j][r];
        const long idx = (row + r) * N + col;
        if (MODE == MODE_BIAS) {
          ((unsigned short*)C)[idx] = f2b(v + bb[j]);
        } else if (MODE == MODE_SB) {
          ((unsigned short*)C)[idx] = f2b(v * scale);
        } else if (MODE == MODE_RES) {
          ((unsigned short*)C)[idx] = f2b(v + b2f(Res[idx]));
        } else {  // MODE_OUT
          const float o = v + bb[j];
          if (f32out) ((float*)C)[idx] = o;
          else        ((unsigned short*)C)[idx] = f2b(o);
        }
      }
    }
  }
}

template <int MODE>
__global__ __launch_bounds__(512, 2) void gemm_nt256(
    const unsigned short* __restrict__ A, const unsigned short* __restrict__ B,
    void* __restrict__ C, const unsigned short* __restrict__ bias,
    const unsigned short* __restrict__ Res, const int* __restrict__ flg,
    int N, int K, float scale, long sA, long sB, long sC, long sR) {
  const int bz = blockIdx.z;
  int bx, by;
  xcd_swizzle(gridDim.x, gridDim.y, bx, by);
  const unsigned short* Rb = (MODE == MODE_RES) ? Res + bz * sR : nullptr;
  void* Cb = (MODE == MODE_OUT) ? (void*)((char*)C)
                                : (void*)((unsigned short*)C + bz * sC);
  gemm256_core<MODE>(A + bz * sA, B + bz * sB, Cb, bias, Rb, flg, N, K, scale,
                     bx, by, 0);
}

// merged Q/K/V projections on the 256x256 core: blockIdx.z selects
// (A,B,C,bias); z==2 (V) stores transposed into the Vt buffer.
struct QkvArgs {
  const unsigned short* A[3];
  const unsigned short* B[3];
  unsigned short* C[3];
  const unsigned short* bias[3];
};
__global__ __launch_bounds__(512, 2) void gemm_qkv(QkvArgs a, int N, int K) {
  const int z = blockIdx.z;
  int bx, by;
  xcd_swizzle(gridDim.x, gridDim.y, bx, by);
  gemm256_core<MODE_BIAS>(a.A[z], a.B[z], a.C[z], a.bias[z], nullptr, nullptr,
                          N, K, 1.f, bx, by, z == 2 ? 1 : 0);
}

// in-place row softmax over 2048 bf16 scores; one block per row; 16B/lane
__global__ __launch_bounds__(256) void softmax_rows(
    unsigned short* __restrict__ SP) {
  unsigned short* s = SP + blockIdx.x * 2048L;
  const int tid = threadIdx.x;
  const ushort8 raw = *(const ushort8*)(s + tid * 8);
  float v[8];
#pragma unroll
  for (int i = 0; i < 8; ++i) v[i] = b2f(raw[i]);
  float m = v[0];
#pragma unroll
  for (int i = 1; i < 8; ++i) m = fmaxf(m, v[i]);
#pragma unroll
  for (int off = 32; off > 0; off >>= 1) m = fmaxf(m, __shfl_xor(m, off));
  __shared__ float redm[4], reds[4];
  if ((tid & 63) == 0) redm[tid >> 6] = m;
  __syncthreads();
  m = fmaxf(fmaxf(redm[0], redm[1]), fmaxf(redm[2], redm[3]));
  float sum = 0.f;
#pragma unroll
  for (int i = 0; i < 8; ++i) {
    v[i] = __expf(v[i] - m);
    sum += v[i];
  }
#pragma unroll
  for (int off = 32; off > 0; off >>= 1) sum += __shfl_xor(sum, off);
  if ((tid & 63) == 0) reds[tid >> 6] = sum;
  __syncthreads();
  sum = reds[0] + reds[1] + reds[2] + reds[3];
  const float inv = 1.0f / sum;
  ushort8 o;
#pragma unroll
  for (int i = 0; i < 8; ++i) o[i] = f2b(v[i] * inv);
  *(ushort8*)(s + tid * 8) = o;
}

extern "C" void kernel_launch(void* const* d_in, const int* in_sizes, int n_in,
                              void* d_out, int out_size, void* d_ws,
                              size_t ws_size, hipStream_t stream) {
  char* ws = (char*)d_ws;
  const long MB = 1 << 20;
  unsigned short* C0  = (unsigned short*)ws;  // bf16 concat of inputs
  unsigned short* xb  = C0;
  unsigned short* ceb = C0 + 8388608;
  unsigned short* Wqb = C0 + 16777216;
  unsigned short* bqb = C0 + 17825792;
  unsigned short* Wkb = C0 + 17826816;
  unsigned short* bkb = C0 + 18875392;
  unsigned short* Wvb = C0 + 18876416;
  unsigned short* bvb = C0 + 19924992;
  unsigned short* Wob = C0 + 19926016;
  unsigned short* bob = C0 + 20974592;
  int*            flg = (int*)(ws + 41 * MB);
  unsigned short* Q   = (unsigned short*)(ws + 42 * MB);  // 42-58
  unsigned short* Kp  = (unsigned short*)(ws + 58 * MB);  // 58-74
  unsigned short* Vt  = (unsigned short*)(ws + 74 * MB);  // 74-90 (V^T direct)
  unsigned short* S   = (unsigned short*)(ws + 90 * MB);  // 90-122 (->P)
  unsigned short* Ar  = Kp;  // reuse K slot after QK^T

  const float scale = 0.03125f;  // 1/sqrt(1024)

  detect_fmt<<<dim3(1), dim3(256), 0, stream>>>((const unsigned short*)d_in[0],
                                                flg);
  CvtArgs ca;
  for (int i = 0; i < 10; ++i) ca.src[i] = d_in[i];
  convert_all<<<dim3(1024), dim3(256), 0, stream>>>(ca, C0, flg);

  // merged QKV projections (256^2 core): M=8192 folded, N=K=1024; V goes out
  // transposed into Vt ([b][1024][2048]).  Grid 4x32x3 = 384 blocks.
  QkvArgs qa;
  qa.A[0] = xb;  qa.A[1] = ceb; qa.A[2] = ceb;
  qa.B[0] = Wqb; qa.B[1] = Wkb; qa.B[2] = Wvb;
  qa.C[0] = Q;   qa.C[1] = Kp;  qa.C[2] = Vt;
  qa.bias[0] = bqb; qa.bias[1] = bkb; qa.bias[2] = bvb;
  gemm_qkv<<<dim3(4, 32, 3), dim3(512), 0, stream>>>(qa, 1024, 1024);

  // S = QK^T * scale (bf16), per batch 2048x2048, K=1024 (256^2 core):
  // grid 8x8x4 = 256 blocks = exactly 1 block/CU.
  gemm_nt256<MODE_SB><<<dim3(8, 8, 4), dim3(512), 0, stream>>>(
      Q, Kp, S, nullptr, nullptr, nullptr, 2048, 1024, scale,
      2048L * 1024, 2048L * 1024, 2048L * 2048, 0);

  // P = softmax(S) in place
  softmax_rows<<<dim3(8192), dim3(256), 0, stream>>>(S);

  // A = x + P@V : per batch M=2048, N=1024, K=2048 (B=Vt, NT).  Old 128^2
  // core: 512 blocks keeps all CUs busy (256^2 grid would be 128 blocks).
  gemm_nt<MODE_RES, 2><<<dim3(8, 16, 4), dim3(256), 0, stream>>>(
      S, Vt, Ar, nullptr, xb, nullptr, 1024, 2048, 1.f,
      2048L * 2048, 1024L * 2048, 2048L * 1024, 2048L * 1024);

  // out = A@Wo^T + bo, written straight to d_out in detected format
  gemm_nt<MODE_OUT, 2><<<dim3(8, 64, 1), dim3(256), 0, stream>>>(
      Ar, Wob, d_out, bob, nullptr, flg, 1024, 1024, 1.f, 0, 0, 0, 0);
}

// Round 4
// 327.812 us; speedup vs baseline: 1.0092x; 1.0092x over previous
//
#include <hip/hip_runtime.h>

// ---------------------------------------------------------------------------
// SpatialTransformer attention, dtype-robust (fp32 vs bf16 storage detect).
// Round 7: post-mortem of the 8-phase 256^2 core (80us, MfmaUtil 25%, bank
// conflicts 0) showed my barrier placement serialized the LDS-read region
// against the MFMA region for all 8 waves (192 b128 reads/tile ~770cyc fully
// exposed + 8 barriers/tile).  Rebuilt the 256^2 K-loop as a chunked
// single-barrier pipeline: per K-tile {stage 8 loads -> opposite buf; R0,R1
// (8+8 ds_reads); lgkm(8) MFMA-k0-lo; R2(4); lgkm(4) MFMA-k1-lo; R3(4);
// lgkm(4) MFMA-k0-hi; lgkm(0) MFMA-k1-hi; vmcnt(0); barrier}.  Read groups
// order-pinned with sched_barrier(0) so the counted lgkm ledger holds.
// T2 swizzle kept (verified: conflicts -> 0).  QKV + QK^T on this core;
// PV and OUT keep the round-5 128x128 core (256-grids there = half-idle).
// ---------------------------------------------------------------------------

typedef __attribute__((ext_vector_type(8))) short short8;
typedef __attribute__((ext_vector_type(8))) unsigned short ushort8;
typedef __attribute__((ext_vector_type(4))) unsigned short ushort4v;
typedef __attribute__((ext_vector_type(4))) float f32x4;

__device__ __forceinline__ float b2f(unsigned short u) {
  union { unsigned int i; float f; } x;
  x.i = ((unsigned int)u) << 16;
  return x.f;
}
__device__ __forceinline__ unsigned short f2b(float f) {
  union { float f; unsigned int i; } x;
  x.f = f;
  unsigned int i = x.i;
  i += 0x7fffu + ((i >> 16) & 1u);  // RNE
  return (unsigned short)(i >> 16);
}

__device__ __forceinline__ void async_copy16(const void* g, void* l) {
  __builtin_amdgcn_global_load_lds(
      (const __attribute__((address_space(1))) unsigned int*)g,
      (__attribute__((address_space(3))) unsigned int*)l, 16, 0, 0);
}

// --- storage-format detector: fp32 storage => even ushorts are mantissa bits
__global__ void detect_fmt(const unsigned short* __restrict__ x, int* flag) {
  __shared__ int cnt;
  if (threadIdx.x == 0) cnt = 0;
  __syncthreads();
  int c = 0;
  for (int i = threadIdx.x * 2; i < 8192; i += 512) {
    unsigned e = (x[i] >> 7) & 0xFF;
    if (e >= 0x90) ++c;
  }
  atomicAdd(&cnt, c);
  __syncthreads();
  if (threadIdx.x == 0) *flag = (cnt > 64) ? 1 : 0;
}

// --- one fused conversion of all 10 inputs into a contiguous bf16 concat
struct CvtArgs { const void* src[10]; };

__global__ __launch_bounds__(256) void convert_all(
    CvtArgs a, unsigned short* __restrict__ dst, const int* __restrict__ flag) {
  const bool f32 = (*flag != 0);
  const long nchunk = 2621952;  // 20975616 / 8
  for (long c = blockIdx.x * 256L + threadIdx.x; c < nchunk;
       c += 1024L * 256) {
    const long flat = c * 8;
    int t; long off;
    if      (flat < 8388608)  { t = 0; off = 0; }
    else if (flat < 16777216) { t = 1; off = 8388608; }
    else if (flat < 17825792) { t = 2; off = 16777216; }
    else if (flat < 17826816) { t = 3; off = 17825792; }
    else if (flat < 18875392) { t = 4; off = 17826816; }
    else if (flat < 18876416) { t = 5; off = 18875392; }
    else if (flat < 19924992) { t = 6; off = 18876416; }
    else if (flat < 19926016) { t = 7; off = 19924992; }
    else if (flat < 20974592) { t = 8; off = 19926016; }
    else                      { t = 9; off = 20974592; }
    const long li = flat - off;
    if (f32) {
      const float* s = (const float*)a.src[t] + li;
      const f32x4 lo = *(const f32x4*)s;
      const f32x4 hi = *(const f32x4*)(s + 4);
      ushort8 o;
      o[0] = f2b(lo[0]); o[1] = f2b(lo[1]); o[2] = f2b(lo[2]); o[3] = f2b(lo[3]);
      o[4] = f2b(hi[0]); o[5] = f2b(hi[1]); o[6] = f2b(hi[2]); o[7] = f2b(hi[3]);
      *(ushort8*)(dst + flat) = o;
    } else {
      *(ushort8*)(dst + flat) =
          *(const ushort8*)((const unsigned short*)a.src[t] + li);
    }
  }
}

#define MODE_BIAS 0  // bf16 out = acc + bias[n]  (vt: transposed V^T store)
#define MODE_RES  2  // bf16 out = acc + res[m,n]
#define MODE_SB   3  // bf16 out = acc * scale
#define MODE_OUT  4  // format-aware out = acc + bias[n]  (fp32 or bf16 store)

// XCD-band swizzle: round-robin XCD = linear%8 (assumed); blocks sharing a
// logical `by` (same A row-tile) land on one XCD, bx sweeping 0..gx.
// Requires gy % 8 == 0 (true for all our grids).
__device__ __forceinline__ void xcd_swizzle(int gx, int gy, int& bx, int& by) {
  const int L = blockIdx.y * gx + blockIdx.x;
  const int r = L & 7, m = L >> 3;
  bx = m % gx;
  by = r * (gy >> 3) + m / gx;
}

// ===========================================================================
// OLD 128x128 core (round-5, verified) — kept for PV (MODE_RES) and OUT.
// ===========================================================================
template <int MODE, int KU>
__device__ __forceinline__ void gemm_core(
    const unsigned short* __restrict__ A, const unsigned short* __restrict__ B,
    void* __restrict__ C, const unsigned short* __restrict__ bias,
    const unsigned short* __restrict__ Res, const int* __restrict__ flg,
    int N, int K, float scale, int bx, int by, int vt) {
  __shared__ __align__(16) unsigned short As[KU * 128 * 32];
  __shared__ __align__(16) unsigned short Bs[KU * 128 * 32];
  const int tid = threadIdx.x;
  const int wave = tid >> 6, lane = tid & 63;
  const int wm = wave >> 1, wn = wave & 1;
  const int quad = lane >> 4, lrow = lane & 15;

  const long arow0 = (long)by * 128 + (tid >> 2);
  const long brow0 = (long)bx * 128 + (tid >> 2);
  const int cstg = (tid & 3) * 8;
  const unsigned short* ag0 = A + arow0 * K + cstg;
  const unsigned short* ag1 = ag0 + 64L * K;
  const unsigned short* bg0 = B + brow0 * K + cstg;
  const unsigned short* bg1 = bg0 + 64L * K;
  char* lA0 = (char*)As + tid * 16;
  char* lA1 = (char*)As + (256 + tid) * 16;
  char* lB0 = (char*)Bs + tid * 16;
  char* lB1 = (char*)Bs + (256 + tid) * 16;

  f32x4 acc[4][4];
#pragma unroll
  for (int i = 0; i < 4; ++i)
#pragma unroll
    for (int j = 0; j < 4; ++j) acc[i][j] = (f32x4){0.f, 0.f, 0.f, 0.f};

  for (int kt = 0; kt < K; kt += 32 * KU) {
#pragma unroll
    for (int u = 0; u < KU; ++u) {
      async_copy16(ag0 + kt + u * 32, lA0 + u * 8192);
      async_copy16(ag1 + kt + u * 32, lA1 + u * 8192);
      async_copy16(bg0 + kt + u * 32, lB0 + u * 8192);
      async_copy16(bg1 + kt + u * 32, lB1 + u * 8192);
    }
    __syncthreads();
#pragma unroll
    for (int u = 0; u < KU; ++u) {
      const unsigned short* Au = As + u * 4096;
      const unsigned short* Bu = Bs + u * 4096;
      short8 af[4], bfr[4];
#pragma unroll
      for (int i = 0; i < 4; ++i)
        af[i] = *(const short8*)(Au + (wm * 64 + i * 16 + lrow) * 32 + quad * 8);
#pragma unroll
      for (int j = 0; j < 4; ++j)
        bfr[j] =
            *(const short8*)(Bu + (wn * 64 + j * 16 + lrow) * 32 + quad * 8);
#pragma unroll
      for (int i = 0; i < 4; ++i)
#pragma unroll
        for (int j = 0; j < 4; ++j)
          acc[i][j] = __builtin_amdgcn_mfma_f32_16x16x32_bf16(
              af[i], bfr[j], acc[i][j], 0, 0, 0);
    }
    __syncthreads();
  }

  const bool f32out = (MODE == MODE_OUT) ? (*flg != 0) : false;
  // C/D layout: col=lane&15, row=(lane>>4)*4+reg (m89-verified)
#pragma unroll
  for (int i = 0; i < 4; ++i) {
    const long row = (long)by * 128 + wm * 64 + i * 16 + quad * 4;
#pragma unroll
    for (int j = 0; j < 4; ++j) {
      const long col = (long)bx * 128 + wn * 64 + j * 16 + lrow;
      if (MODE == MODE_BIAS && vt) {
        const float bb = b2f(bias[col]);
        ushort4v pk;
#pragma unroll
        for (int r = 0; r < 4; ++r) pk[r] = f2b(acc[i][j][r] + bb);
        const long b = row >> 11, kvr = row & 2047;
        *(ushort4v*)((unsigned short*)C + b * 2097152 + col * 2048 + kvr) = pk;
        continue;
      }
#pragma unroll
      for (int r = 0; r < 4; ++r) {
        const float v = acc[i][j][r];
        const long idx = (row + r) * N + col;
        if (MODE == MODE_BIAS) {
          ((unsigned short*)C)[idx] = f2b(v + b2f(bias[col]));
        } else if (MODE == MODE_SB) {
          ((unsigned short*)C)[idx] = f2b(v * scale);
        } else if (MODE == MODE_RES) {
          ((unsigned short*)C)[idx] = f2b(v + b2f(Res[idx]));
        } else {  // MODE_OUT
          const float o = v + b2f(bias[col]);
          if (f32out) ((float*)C)[idx] = o;
          else        ((unsigned short*)C)[idx] = f2b(o);
        }
      }
    }
  }
}

template <int MODE, int KU>
__global__ __launch_bounds__(256, 2) void gemm_nt(
    const unsigned short* __restrict__ A, const unsigned short* __restrict__ B,
    void* __restrict__ C, const unsigned short* __restrict__ bias,
    const unsigned short* __restrict__ Res, const int* __restrict__ flg,
    int N, int K, float scale, long sA, long sB, long sC, long sR) {
  const int bz = blockIdx.z;
  int bx, by;
  xcd_swizzle(gridDim.x, gridDim.y, bx, by);
  const unsigned short* Rb = (MODE == MODE_RES) ? Res + bz * sR : nullptr;
  void* Cb = (MODE == MODE_OUT) ? (void*)((char*)C)
                                : (void*)((unsigned short*)C + bz * sC);
  gemm_core<MODE, KU>(A + bz * sA, B + bz * sB, Cb, bias, Rb, flg, N, K, scale,
                      bx, by, 0);
}

// ===========================================================================
// 256x256 chunk-pipelined core (round 7), 512 threads = 8 waves (2M x 4N),
// BK=64, LDS 128 KiB double-buffered, per-wave output 128x64.
//
// LDS (bytes): A bufs at 0/32768, B bufs at 65536/98304; each buf = 2 halves
// x 16 KiB (128 rows x 64 cols bf16, row stride 128 B).  Swizzle: 16B chunk
// (row, ch) stored at chunk position ch ^ (row&7) via pre-swizzled GLOBAL
// source (rule #21); reads apply the same involution.  Verified: conflicts=0.
//
// K-loop (1 barrier + 1 vmcnt per K-tile):
//   stage 4 halves of tile t+1 -> buf[t^1] (8 loads; old readers of that
//     buffer finished before this tile's entry barrier)
//   R0 (8 reads: A-lo k0 + B k0) | R1 (8: A-lo k1 + B k1)   [order pinned]
//   lgkm(8)  -> MFMA chunk C0 = m0-3 x n0-3 x k0   (16 indep MFMA)
//   R2 (4: A-hi k0);  lgkm(4) -> C1 = m0-3 x k1
//   R3 (4: A-hi k1);  lgkm(4) -> C2 = m4-7 x k0
//   lgkm(0) -> C3 = m4-7 x k1
//   vmcnt(0) (stages issued a full tile ago) ; s_barrier certifies t+1.
// Counted-lgkm ledger: 16 out -> lgkm(8)=R0; +4 -> lgkm(4)=R1; +4 ->
// lgkm(4)=R2; lgkm(0)=R3.  sched_barrier(0) pins each group boundary.
// ===========================================================================
template <int MODE>
__device__ __forceinline__ void gemm256_core(
    const unsigned short* __restrict__ A, const unsigned short* __restrict__ B,
    void* __restrict__ C, const unsigned short* __restrict__ bias,
    const unsigned short* __restrict__ Res, const int* __restrict__ flg,
    int N, int K, float scale, int bx, int by, int vt) {
  __shared__ __align__(16) unsigned short lds[65536];  // 128 KiB
  const int tid = threadIdx.x;
  const int wave = tid >> 6, lane = tid & 63;
  const int wm = wave >> 2, wn = wave & 3;        // 2 x 4 wave grid
  const int quad = lane >> 4, lrow = lane & 15;
  const int NT = K >> 6;                           // K-tiles of 64

  // --- staging map: thread tid covers linear LDS bytes tid*16 (+8192 for
  // issue 1) of the target half; logical source chunk is pre-swizzled.
  const int srow = tid >> 3;                       // 0..63 (issue0 row)
  const int sch = (tid & 7) ^ (srow & 7);          // swizzled source chunk
  const unsigned short* gA = A + (long)(by * 256 + srow) * K + sch * 8;
  const unsigned short* gB = B + (long)(bx * 256 + srow) * K + sch * 8;
  char* const ldst = (char*)lds + tid * 16;

  auto stageA = [&](int ts, int h) {
    const unsigned short* g = gA + (long)h * 128 * K + ts * 64;
    char* l = ldst + (ts & 1) * 32768 + h * 16384;
    async_copy16(g, l);
    async_copy16(g + (long)64 * K, l + 8192);
  };
  auto stageB = [&](int ts, int h) {
    const unsigned short* g = gB + (long)h * 128 * K + ts * 64;
    char* l = ldst + 65536 + (ts & 1) * 32768 + h * 16384;
    async_copy16(g, l);
    async_copy16(g + (long)64 * K, l + 8192);
  };

  // fragment-read swizzled chunk offsets (elements); row&7 == lrow&7
  const int chk0 = ((quad) ^ (lrow & 7)) << 3;       // k-slice 0
  const int chk1 = ((4 + quad) ^ (lrow & 7)) << 3;   // k-slice 1

  f32x4 acc[8][4];
#pragma unroll
  for (int i = 0; i < 8; ++i)
#pragma unroll
    for (int j = 0; j < 4; ++j) acc[i][j] = (f32x4){0.f, 0.f, 0.f, 0.f};

  // --- prologue: stage tile 0 completely, drain, certify
  stageA(0, 0); stageA(0, 1); stageB(0, 0); stageB(0, 1);
  asm volatile("s_waitcnt vmcnt(0)" ::: "memory");
  __builtin_amdgcn_s_barrier();

  for (int t = 0; t < NT; ++t) {
    const unsigned short* Au = lds + (t & 1) * 16384 + (wm * 128 + lrow) * 64;
    const unsigned short* Bu =
        lds + 32768 + (t & 1) * 16384 + (wn * 64 + lrow) * 64;
    short8 alo[4][2], ahi[4][2], b[4][2];

    // R0: A-lo k0 (4) + B k0 (4)
#pragma unroll
    for (int i = 0; i < 4; ++i)
      alo[i][0] = *(const short8*)(Au + i * 1024 + chk0);
#pragma unroll
    for (int j = 0; j < 4; ++j)
      b[j][0] = *(const short8*)(Bu + j * 1024 + chk0);
    __builtin_amdgcn_sched_barrier(0);
    // R1: A-lo k1 (4) + B k1 (4)
#pragma unroll
    for (int i = 0; i < 4; ++i)
      alo[i][1] = *(const short8*)(Au + i * 1024 + chk1);
#pragma unroll
    for (int j = 0; j < 4; ++j)
      b[j][1] = *(const short8*)(Bu + j * 1024 + chk1);
    __builtin_amdgcn_sched_barrier(0);

    // stage tile t+1 into the opposite buffer (max slack to the vmcnt)
    if (t + 1 < NT) {
      stageA(t + 1, 0); stageA(t + 1, 1);
      stageB(t + 1, 0); stageB(t + 1, 1);
    }
    __builtin_amdgcn_sched_barrier(0);

    // C0: m0-3 x n0-3 x k0  (needs R0)
    asm volatile("s_waitcnt lgkmcnt(8)" ::: "memory");
    __builtin_amdgcn_sched_barrier(0);
    __builtin_amdgcn_s_setprio(1);
#pragma unroll
    for (int i = 0; i < 4; ++i)
#pragma unroll
      for (int j = 0; j < 4; ++j)
        acc[i][j] = __builtin_amdgcn_mfma_f32_16x16x32_bf16(
            alo[i][0], b[j][0], acc[i][j], 0, 0, 0);
    __builtin_amdgcn_s_setprio(0);
    __builtin_amdgcn_sched_barrier(0);

    // R2: A-hi k0 (4)
#pragma unroll
    for (int i = 0; i < 4; ++i)
      ahi[i][0] = *(const short8*)(Au + (i + 4) * 1024 + chk0);
    __builtin_amdgcn_sched_barrier(0);

    // C1: m0-3 x n0-3 x k1  (needs R1)
    asm volatile("s_waitcnt lgkmcnt(4)" ::: "memory");
    __builtin_amdgcn_sched_barrier(0);
    __builtin_amdgcn_s_setprio(1);
#pragma unroll
    for (int i = 0; i < 4; ++i)
#pragma unroll
      for (int j = 0; j < 4; ++j)
        acc[i][j] = __builtin_amdgcn_mfma_f32_16x16x32_bf16(
            alo[i][1], b[j][1], acc[i][j], 0, 0, 0);
    __builtin_amdgcn_s_setprio(0);
    __builtin_amdgcn_sched_barrier(0);

    // R3: A-hi k1 (4)
#pragma unroll
    for (int i = 0; i < 4; ++i)
      ahi[i][1] = *(const short8*)(Au + (i + 4) * 1024 + chk1);
    __builtin_amdgcn_sched_barrier(0);

    // C2: m4-7 x n0-3 x k0  (needs R2)
    asm volatile("s_waitcnt lgkmcnt(4)" ::: "memory");
    __builtin_amdgcn_sched_barrier(0);
    __builtin_amdgcn_s_setprio(1);
#pragma unroll
    for (int i = 0; i < 4; ++i)
#pragma unroll
      for (int j = 0; j < 4; ++j)
        acc[i + 4][j] = __builtin_amdgcn_mfma_f32_16x16x32_bf16(
            ahi[i][0], b[j][0], acc[i + 4][j], 0, 0, 0);
    __builtin_amdgcn_s_setprio(0);
    __builtin_amdgcn_sched_barrier(0);

    // C3: m4-7 x n0-3 x k1  (needs R3)
    asm volatile("s_waitcnt lgkmcnt(0)" ::: "memory");
    __builtin_amdgcn_sched_barrier(0);
    __builtin_amdgcn_s_setprio(1);
#pragma unroll
    for (int i = 0; i < 4; ++i)
#pragma unroll
      for (int j = 0; j < 4; ++j)
        acc[i + 4][j] = __builtin_amdgcn_mfma_f32_16x16x32_bf16(
            ahi[i][1], b[j][1], acc[i + 4][j], 0, 0, 0);
    __builtin_amdgcn_s_setprio(0);
    __builtin_amdgcn_sched_barrier(0);

    // close tile: own stage loads drained, then barrier certifies t+1 data
    // (also closes the read window on buf[t&1] before t+1 stages into it).
    asm volatile("s_waitcnt vmcnt(0)" ::: "memory");
    __builtin_amdgcn_s_barrier();
  }

  // --- epilogue: C/D layout col=lane&15, row=(lane>>4)*4+reg (m89-verified)
  const bool f32out = (MODE == MODE_OUT) ? (*flg != 0) : false;
  float bb[4];
  if (MODE == MODE_BIAS || MODE == MODE_OUT) {
#pragma unroll
    for (int j = 0; j < 4; ++j)
      bb[j] = b2f(bias[(long)bx * 256 + wn * 64 + j * 16 + lrow]);
  }
#pragma unroll
  for (int i = 0; i < 8; ++i) {
    const long row = (long)by * 256 + wm * 128 + i * 16 + quad * 4;
#pragma unroll
    for (int j = 0; j < 4; ++j) {
      const long col = (long)bx * 256 + wn * 64 + j * 16 + lrow;
      if (MODE == MODE_BIAS && vt) {
        // V^T store: Vt[b][col][kv], 4 consecutive rows -> one 8B store
        ushort4v pk;
#pragma unroll
        for (int r = 0; r < 4; ++r) pk[r] = f2b(acc[i][j][r] + bb[j]);
        const long b = row >> 11, kvr = row & 2047;
        *(ushort4v*)((unsigned short*)C + b * 2097152 + col * 2048 + kvr) = pk;
        continue;
      }
#pragma unroll
      for (int r = 0; r < 4; ++r) {
        const float v = acc[i][j][r];
        const long idx = (row + r) * N + col;
        if (MODE == MODE_BIAS) {
          ((unsigned short*)C)[idx] = f2b(v + bb[j]);
        } else if (MODE == MODE_SB) {
          ((unsigned short*)C)[idx] = f2b(v * scale);
        } else if (MODE == MODE_RES) {
          ((unsigned short*)C)[idx] = f2b(v + b2f(Res[idx]));
        } else {  // MODE_OUT
          const float o = v + bb[j];
          if (f32out) ((float*)C)[idx] = o;
          else        ((unsigned short*)C)[idx] = f2b(o);
        }
      }
    }
  }
}

template <int MODE>
__global__ __launch_bounds__(512, 2) void gemm_nt256(
    const unsigned short* __restrict__ A, const unsigned short* __restrict__ B,
    void* __restrict__ C, const unsigned short* __restrict__ bias,
    const unsigned short* __restrict__ Res, const int* __restrict__ flg,
    int N, int K, float scale, long sA, long sB, long sC, long sR) {
  const int bz = blockIdx.z;
  int bx, by;
  xcd_swizzle(gridDim.x, gridDim.y, bx, by);
  const unsigned short* Rb = (MODE == MODE_RES) ? Res + bz * sR : nullptr;
  void* Cb = (MODE == MODE_OUT) ? (void*)((char*)C)
                                : (void*)((unsigned short*)C + bz * sC);
  gemm256_core<MODE>(A + bz * sA, B + bz * sB, Cb, bias, Rb, flg, N, K, scale,
                     bx, by, 0);
}

// merged Q/K/V projections on the 256x256 core: blockIdx.z selects
// (A,B,C,bias); z==2 (V) stores transposed into the Vt buffer.
struct QkvArgs {
  const unsigned short* A[3];
  const unsigned short* B[3];
  unsigned short* C[3];
  const unsigned short* bias[3];
};
__global__ __launch_bounds__(512, 2) void gemm_qkv(QkvArgs a, int N, int K) {
  const int z = blockIdx.z;
  int bx, by;
  xcd_swizzle(gridDim.x, gridDim.y, bx, by);
  gemm256_core<MODE_BIAS>(a.A[z], a.B[z], a.C[z], a.bias[z], nullptr, nullptr,
                          N, K, 1.f, bx, by, z == 2 ? 1 : 0);
}

// in-place row softmax over 2048 bf16 scores; one block per row; 16B/lane
__global__ __launch_bounds__(256) void softmax_rows(
    unsigned short* __restrict__ SP) {
  unsigned short* s = SP + blockIdx.x * 2048L;
  const int tid = threadIdx.x;
  const ushort8 raw = *(const ushort8*)(s + tid * 8);
  float v[8];
#pragma unroll
  for (int i = 0; i < 8; ++i) v[i] = b2f(raw[i]);
  float m = v[0];
#pragma unroll
  for (int i = 1; i < 8; ++i) m = fmaxf(m, v[i]);
#pragma unroll
  for (int off = 32; off > 0; off >>= 1) m = fmaxf(m, __shfl_xor(m, off));
  __shared__ float redm[4], reds[4];
  if ((tid & 63) == 0) redm[tid >> 6] = m;
  __syncthreads();
  m = fmaxf(fmaxf(redm[0], redm[1]), fmaxf(redm[2], redm[3]));
  float sum = 0.f;
#pragma unroll
  for (int i = 0; i < 8; ++i) {
    v[i] = __expf(v[i] - m);
    sum += v[i];
  }
#pragma unroll
  for (int off = 32; off > 0; off >>= 1) sum += __shfl_xor(sum, off);
  if ((tid & 63) == 0) reds[tid >> 6] = sum;
  __syncthreads();
  sum = reds[0] + reds[1] + reds[2] + reds[3];
  const float inv = 1.0f / sum;
  ushort8 o;
#pragma unroll
  for (int i = 0; i < 8; ++i) o[i] = f2b(v[i] * inv);
  *(ushort8*)(s + tid * 8) = o;
}

extern "C" void kernel_launch(void* const* d_in, const int* in_sizes, int n_in,
                              void* d_out, int out_size, void* d_ws,
                              size_t ws_size, hipStream_t stream) {
  char* ws = (char*)d_ws;
  const long MB = 1 << 20;
  unsigned short* C0  = (unsigned short*)ws;  // bf16 concat of inputs
  unsigned short* xb  = C0;
  unsigned short* ceb = C0 + 8388608;
  unsigned short* Wqb = C0 + 16777216;
  unsigned short* bqb = C0 + 17825792;
  unsigned short* Wkb = C0 + 17826816;
  unsigned short* bkb = C0 + 18875392;
  unsigned short* Wvb = C0 + 18876416;
  unsigned short* bvb = C0 + 19924992;
  unsigned short* Wob = C0 + 19926016;
  unsigned short* bob = C0 + 20974592;
  int*            flg = (int*)(ws + 41 * MB);
  unsigned short* Q   = (unsigned short*)(ws + 42 * MB);  // 42-58
  unsigned short* Kp  = (unsigned short*)(ws + 58 * MB);  // 58-74
  unsigned short* Vt  = (unsigned short*)(ws + 74 * MB);  // 74-90 (V^T direct)
  unsigned short* S   = (unsigned short*)(ws + 90 * MB);  // 90-122 (->P)
  unsigned short* Ar  = Kp;  // reuse K slot after QK^T

  const float scale = 0.03125f;  // 1/sqrt(1024)

  detect_fmt<<<dim3(1), dim3(256), 0, stream>>>((const unsigned short*)d_in[0],
                                                flg);
  CvtArgs ca;
  for (int i = 0; i < 10; ++i) ca.src[i] = d_in[i];
  convert_all<<<dim3(1024), dim3(256), 0, stream>>>(ca, C0, flg);

  // merged QKV projections (256^2 chunk-pipelined core): M=8192 folded,
  // N=K=1024; V transposed into Vt ([b][1024][2048]).  Grid 4x32x3 = 384.
  QkvArgs qa;
  qa.A[0] = xb;  qa.A[1] = ceb; qa.A[2] = ceb;
  qa.B[0] = Wqb; qa.B[1] = Wkb; qa.B[2] = Wvb;
  qa.C[0] = Q;   qa.C[1] = Kp;  qa.C[2] = Vt;
  qa.bias[0] = bqb; qa.bias[1] = bkb; qa.bias[2] = bvb;
  gemm_qkv<<<dim3(4, 32, 3), dim3(512), 0, stream>>>(qa, 1024, 1024);

  // S = QK^T * scale (bf16), per batch 2048x2048, K=1024 (256^2 core):
  // grid 8x8x4 = 256 blocks = exactly 1 block/CU.
  gemm_nt256<MODE_SB><<<dim3(8, 8, 4), dim3(512), 0, stream>>>(
      Q, Kp, S, nullptr, nullptr, nullptr, 2048, 1024, scale,
      2048L * 1024, 2048L * 1024, 2048L * 2048, 0);

  // P = softmax(S) in place
  softmax_rows<<<dim3(8192), dim3(256), 0, stream>>>(S);

  // A = x + P@V : per batch M=2048, N=1024, K=2048 (B=Vt, NT).  Old 128^2
  // core: 512 blocks keeps all CUs busy (256^2 grid would be 128 blocks).
  gemm_nt<MODE_RES, 2><<<dim3(8, 16, 4), dim3(256), 0, stream>>>(
      S, Vt, Ar, nullptr, xb, nullptr, 1024, 2048, 1.f,
      2048L * 2048, 1024L * 2048, 2048L * 1024, 2048L * 1024);

  // out = A@Wo^T + bo, written straight to d_out in detected format
  gemm_nt<MODE_OUT, 2><<<dim3(8, 64, 1), dim3(256), 0, stream>>>(
      Ar, Wob, d_out, bob, nullptr, flg, 1024, 1024, 1.f, 0, 0, 0, 0);
}